// Round 4
// baseline (612.896 us; speedup 1.0000x reference)
//
#include <hip/hip_runtime.h>
#include <stdint.h>

#define M_DIM 8192
#define N_DIM 4096
#define K_DIM 4096

typedef __attribute__((ext_vector_type(4))) float f32x4;
typedef __attribute__((ext_vector_type(8))) __bf16 bf16x8;

__device__ __forceinline__ unsigned short f2bf(float f) {
  unsigned int u = __builtin_bit_cast(unsigned int, f);
  u += 0x7FFFu + ((u >> 16) & 1u);   // round-to-nearest-even
  return (unsigned short)(u >> 16);
}

__device__ __forceinline__ void load16_lds(const void* g, void* l) {
  __builtin_amdgcn_global_load_lds(
      (__attribute__((address_space(1))) void*)g,
      (__attribute__((address_space(3))) void*)l,
      16, 0, 0);
}

#define WAITVM(N) asm volatile("s_waitcnt vmcnt(" #N ")" ::: "memory")
#define LGKM0()   asm volatile("s_waitcnt lgkmcnt(0)" ::: "memory")
#define BARRIER() __builtin_amdgcn_s_barrier()

// ---------------------------------------------------------------------------
// Kernel 1: x f32 -> bf16 (vectorized 8 elems/thread)
// ---------------------------------------------------------------------------
__global__ __launch_bounds__(256) void cvt_x_kernel(const float* __restrict__ x,
                                                    unsigned short* __restrict__ xb) {
  const int n8 = (M_DIM * K_DIM) / 8;
  int i = blockIdx.x * blockDim.x + threadIdx.x;
  const int stride = gridDim.x * blockDim.x;
  for (; i < n8; i += stride) {
    const float4* p = (const float4*)x + (size_t)i * 2;
    const float4 a = p[0];
    const float4 b = p[1];
    uint4 o;
    o.x = (unsigned)f2bf(a.x) | ((unsigned)f2bf(a.y) << 16);
    o.y = (unsigned)f2bf(a.z) | ((unsigned)f2bf(a.w) << 16);
    o.z = (unsigned)f2bf(b.x) | ((unsigned)f2bf(b.y) << 16);
    o.w = (unsigned)f2bf(b.z) | ((unsigned)f2bf(b.w) << 16);
    ((uint4*)xb)[i] = o;
  }
}

// ---------------------------------------------------------------------------
// Kernel 2: Wb[o][i] = bf16(W[o][i] + 2 * sum_r B[o][r]*A[r][i])
// ---------------------------------------------------------------------------
__global__ __launch_bounds__(256) void build_wb_kernel(const float* __restrict__ W,
                                                       const float* __restrict__ B_lora,
                                                       const float* __restrict__ A_lora,
                                                       unsigned short* __restrict__ wb) {
  __shared__ float As[64][17];
  __shared__ float Bs[64][17];
  const int t = threadIdx.x;
  const int i0 = blockIdx.x * 64;
  const int o0 = blockIdx.y * 64;
  {
    const int c = t & 63;
    #pragma unroll
    for (int rr = (t >> 6); rr < 16; rr += 4)
      As[c][rr] = A_lora[rr * K_DIM + i0 + c];
    const int r2 = t & 15;
    #pragma unroll
    for (int oo = (t >> 4); oo < 64; oo += 16)
      Bs[oo][r2] = B_lora[(o0 + oo) * 16 + r2];
  }
  __syncthreads();
  const int ci = t & 63;
  const int og = t >> 6;
  float areg[16];
  #pragma unroll
  for (int r = 0; r < 16; ++r) areg[r] = As[ci][r];
  const int i = i0 + ci;
  #pragma unroll 4
  for (int j = 0; j < 16; ++j) {
    const int ol = og * 16 + j;
    float d = 0.f;
    #pragma unroll
    for (int r = 0; r < 16; ++r) d += Bs[ol][r] * areg[r];
    const size_t idx = (size_t)(o0 + ol) * K_DIM + i;
    wb[idx] = f2bf(W[idx] + 2.0f * d);
  }
}

// ---------------------------------------------------------------------------
// Kernel 3: 256x256 8-phase bf16 MFMA GEMM (T2+T3+T4+T5), BK=64, 8 waves.
// out[m][n] = sum_k xb[m][k]*wb[n][k] + bias[n] + 2*dbias[n]
//
// R4 change vs R3 (which hit 895 TF, MfmaUtil 38.6%): deepen the vmcnt
// pipeline to 3 half-tiles in flight (uniform vmcnt(6), m201 steady state)
// by shifting the A0 stage one phase earlier: ph4 of tile t stages A0(t+2)
// into buffer `cur` (its A0 region's last read was ph1 of t, barrier-sep).
// Stage cadence: A0(t+1)@ph4(t-1), B0(t+1)@ph1(t), B1(t+1)@ph2(t),
// A1(t+1)@ph3(t). Waits: vmcnt(6) at ph1/ph2/ph4 (each lands exactly the
// half needed next). Also: builtin s_barrier + explicit lgkmcnt(0) before
// each MFMA cluster + stage-before-read ordering (m201 template form).
// LDS swizzle/permutation unchanged (R3 measured 0 bank conflicts).
// ---------------------------------------------------------------------------
__global__ __launch_bounds__(512, 2) void gemm_kernel(const unsigned short* __restrict__ xb,
                                                      const unsigned short* __restrict__ wb,
                                                      const float* __restrict__ bias,
                                                      const float* __restrict__ dbias,
                                                      float* __restrict__ out) {
  constexpr int BK = 64;
  constexpr int NT = K_DIM / BK;                     // 64
  __shared__ char As[65536];                         // 2 x 32KB
  __shared__ char Bs[65536];                         // 2 x 32KB

  const int t = threadIdx.x;
  const int w = t >> 6, l = t & 63;
  const int wr = w >> 2, wc = w & 3;                 // 2M x 4N waves
  constexpr int NBN = N_DIM / 256;                   // 16
  constexpr int NWG = (M_DIM / 256) * NBN;           // 512 (div by 8)
  int bid = (int)blockIdx.x;
  bid = (bid & 7) * (NWG >> 3) + (bid >> 3);         // bijective XCD swizzle
  const int m0 = (bid / NBN) * 256;
  const int n0 = (bid % NBN) * 256;

  // ---- staging constants (per thread) ----
  const int trow = t >> 3;                           // 0..63
  const int scol = ((t & 7) ^ (trow & 7)) * 8;       // inverse-swizzled src chunk
  const int rowoffA[4] = {0, 128, 64, 192};          // slots: A0={0,1} A1={2,3}
  const int ldsoffA[4] = {0, 16384, 8192, 24576};
  const unsigned short* gAp[4];
  #pragma unroll
  for (int j = 0; j < 4; ++j)
    gAp[j] = xb + (size_t)(m0 + rowoffA[j] + trow) * K_DIM + scol;
  const unsigned short* gBp[4];
  #pragma unroll
  for (int j = 0; j < 4; ++j) {
    const int rp = j * 64 + trow;
    const int gr = (rp & 31) + ((rp >> 5) & 3) * 64 + (rp >> 7) * 32;
    gBp[j] = wb + (size_t)(n0 + gr) * K_DIM + scol;
  }
  const int wlds = w * 1024;                         // wave-uniform lane block

  // ---- ds_read constants ----
  const int swz = (l & 7) << 4;
  const int rdk = (l >> 4) * 16;
  const int rdA = (wr * 128 + (l & 15)) * 128;       // A frag base (bytes)
  const int rdB = (wc * 32 + (l & 15)) * 128;        // B frag base (bytes)

  f32x4 acc[8][4];
  #pragma unroll
  for (int i = 0; i < 8; ++i)
    #pragma unroll
    for (int j = 0; j < 4; ++j) acc[i][j] = f32x4{0.f, 0.f, 0.f, 0.f};
  bf16x8 af[4][2], bf[4][2];

#define STAGE_A(CUR, SLOT, KT) \
  load16_lds(gAp[SLOT] + (KT), As + (CUR) * 32768 + ldsoffA[SLOT] + wlds)
#define STAGE_B(CUR, SLOT, KT) \
  load16_lds(gBp[SLOT] + (KT), Bs + (CUR) * 32768 + (SLOT) * 8192 + wlds)

#define READ_AH(CUR, MH)                                                      \
  {                                                                           \
    const char* base_ = As + (CUR) * 32768 + rdA + (MH) * 8192;               \
    _Pragma("unroll") for (int mf_ = 0; mf_ < 4; ++mf_)                       \
      _Pragma("unroll") for (int ks_ = 0; ks_ < 2; ++ks_)                     \
        af[mf_][ks_] = *(const bf16x8*)(base_ + mf_ * 2048 +                  \
                                        ((ks_ * 64 + rdk) ^ swz));            \
  }
#define READ_BH(CUR, NH)                                                      \
  {                                                                           \
    const char* base_ = Bs + (CUR) * 32768 + rdB + (NH) * 16384;              \
    _Pragma("unroll") for (int nf_ = 0; nf_ < 2; ++nf_)                       \
      _Pragma("unroll") for (int ks_ = 0; ks_ < 2; ++ks_)                     \
        bf[(NH) * 2 + nf_][ks_] = *(const bf16x8*)(base_ + nf_ * 2048 +       \
                                                   ((ks_ * 64 + rdk) ^ swz)); \
  }
#define QUAD(MH, NH)                                                          \
  {                                                                           \
    __builtin_amdgcn_s_setprio(1);                                            \
    _Pragma("unroll") for (int mf_ = 0; mf_ < 4; ++mf_)                       \
      _Pragma("unroll") for (int nf_ = 0; nf_ < 2; ++nf_)                     \
        _Pragma("unroll") for (int ks_ = 0; ks_ < 2; ++ks_)                   \
          acc[(MH) * 4 + mf_][(NH) * 2 + nf_] =                               \
              __builtin_amdgcn_mfma_f32_16x16x32_bf16(                        \
                  af[mf_][ks_], bf[(NH) * 2 + nf_][ks_],                      \
                  acc[(MH) * 4 + mf_][(NH) * 2 + nf_], 0, 0, 0);              \
    __builtin_amdgcn_s_setprio(0);                                            \
  }

  // ---- prologue: stage all of tile 0 + A0(tile 1); 3 halves stay in flight
  STAGE_A(0, 0, 0); STAGE_A(0, 1, 0);   // A0(t0)
  STAGE_B(0, 0, 0); STAGE_B(0, 1, 0);   // B0(t0)
  STAGE_B(0, 2, 0); STAGE_B(0, 3, 0);   // B1(t0)
  STAGE_A(0, 2, 0); STAGE_A(0, 3, 0);   // A1(t0)
  STAGE_A(1, 0, BK); STAGE_A(1, 1, BK); // A0(t1)
  WAITVM(6);   // A0,B0(t0) landed; B1,A1(t0),A0(t1) may be in flight
  BARRIER();

  int cur = 0;
  for (int kt = 0; kt < NT - 1; ++kt) {
    const int kn = (kt + 1) * BK;
    const int nxt = cur ^ 1;
    // phase 1: stage B0(t+1); read+compute quadrant (0,0)
    STAGE_B(nxt, 0, kn); STAGE_B(nxt, 1, kn);
    READ_AH(cur, 0); READ_BH(cur, 0);
    BARRIER(); LGKM0(); QUAD(0, 0); WAITVM(6); BARRIER();   // B1(t) landed
    // phase 2: stage B1(t+1); quadrant (0,1)
    STAGE_B(nxt, 2, kn); STAGE_B(nxt, 3, kn);
    READ_BH(cur, 1);
    BARRIER(); LGKM0(); QUAD(0, 1); WAITVM(6); BARRIER();   // A1(t) landed
    // phase 3: stage A1(t+1); quadrant (1,1)
    STAGE_A(nxt, 2, kn); STAGE_A(nxt, 3, kn);
    READ_AH(cur, 1);
    BARRIER(); LGKM0(); QUAD(1, 1); BARRIER();
    // phase 4: stage A0(t+2) into cur (A0 region free since ph1); quad (1,0)
    if (kt < NT - 2) {
      STAGE_A(cur, 0, kn + BK); STAGE_A(cur, 1, kn + BK);
      BARRIER(); QUAD(1, 0); WAITVM(6); BARRIER();          // A0,B0(t+1) landed
    } else {
      BARRIER(); QUAD(1, 0); WAITVM(4); BARRIER();          // A0,B0(t+1) landed
    }
    cur = nxt;
  }
  // ---- final tile: outstanding = B1,A1; drain 2 -> 0 ----
  READ_AH(cur, 0); READ_BH(cur, 0);
  BARRIER(); LGKM0(); QUAD(0, 0); WAITVM(2); BARRIER();
  READ_BH(cur, 1);
  BARRIER(); LGKM0(); QUAD(0, 1); WAITVM(0); BARRIER();
  READ_AH(cur, 1);
  LGKM0(); QUAD(1, 1); QUAD(1, 0);

  // ---- epilogue: C/D layout col=l&15, row=4*(l>>4)+j ----
  float bv[4];
  #pragma unroll
  for (int nf = 0; nf < 4; ++nf) {
    const int c = n0 + wc * 64 + nf * 16 + (l & 15);
    bv[nf] = bias[c] + 2.0f * dbias[c];
  }
  #pragma unroll
  for (int mf = 0; mf < 8; ++mf) {
    const int r0 = m0 + wr * 128 + mf * 16 + ((l >> 4) << 2);
    #pragma unroll
    for (int nf = 0; nf < 4; ++nf) {
      const int c = n0 + wc * 64 + nf * 16 + (l & 15);
      const f32x4 v = acc[mf][nf];
      #pragma unroll
      for (int j = 0; j < 4; ++j)
        out[(size_t)(r0 + j) * N_DIM + c] = v[j] + bv[nf];
    }
  }
#undef STAGE_A
#undef STAGE_B
#undef READ_AH
#undef READ_BH
#undef QUAD
}

// ---------------------------------------------------------------------------
// Fallback path (tiny workspace): xa = x @ A^T, then f32 VALU GEMM + epilogue
// ---------------------------------------------------------------------------
__global__ __launch_bounds__(256) void xa_kernel(const float* __restrict__ x,
                                                 const float* __restrict__ A_lora,
                                                 float* __restrict__ xa) {
  const int m = blockIdx.x;
  const int t = threadIdx.x;
  float acc[16];
  #pragma unroll
  for (int r = 0; r < 16; ++r) acc[r] = 0.f;
  const float* xr = x + (size_t)m * K_DIM;
  for (int k = t; k < K_DIM; k += 256) {
    const float xv = xr[k];
    #pragma unroll
    for (int r = 0; r < 16; ++r) acc[r] += xv * A_lora[r * K_DIM + k];
  }
  __shared__ float red[16][4];
  #pragma unroll
  for (int r = 0; r < 16; ++r) {
    float v = acc[r];
    for (int off = 32; off > 0; off >>= 1) v += __shfl_down(v, off, 64);
    if ((t & 63) == 0) red[r][t >> 6] = v;
  }
  __syncthreads();
  if (t < 16) xa[(size_t)m * 16 + t] = red[t][0] + red[t][1] + red[t][2] + red[t][3];
}

__global__ __launch_bounds__(256) void fgemm_kernel(const float* __restrict__ x,
                                                    const float* __restrict__ W,
                                                    const float* __restrict__ bias,
                                                    const float* __restrict__ B_lora,
                                                    const float* __restrict__ dbias,
                                                    const float* __restrict__ xa,
                                                    float* __restrict__ out) {
  __shared__ float As[64][17];
  __shared__ float Ws[64][17];
  const int t = threadIdx.x;
  const int m0 = (blockIdx.x >> 6) * 64;
  const int n0 = (blockIdx.x & 63) * 64;
  const int tx = t & 15, ty = t >> 4;
  float c[4][4] = {};
  for (int kt = 0; kt < K_DIM; kt += 16) {
    #pragma unroll
    for (int e = 0; e < 4; ++e) {
      const int q = t + e * 256;
      const int r = q >> 4, k = q & 15;
      As[r][k] = x[(size_t)(m0 + r) * K_DIM + kt + k];
      Ws[r][k] = W[(size_t)(n0 + r) * K_DIM + kt + k];
    }
    __syncthreads();
    #pragma unroll
    for (int k = 0; k < 16; ++k) {
      float a[4], b[4];
      #pragma unroll
      for (int ii = 0; ii < 4; ++ii) a[ii] = As[ty * 4 + ii][k];
      #pragma unroll
      for (int jj = 0; jj < 4; ++jj) b[jj] = Ws[tx * 4 + jj][k];
      #pragma unroll
      for (int ii = 0; ii < 4; ++ii)
        #pragma unroll
        for (int jj = 0; jj < 4; ++jj) c[ii][jj] += a[ii] * b[jj];
    }
    __syncthreads();
  }
  #pragma unroll
  for (int ii = 0; ii < 4; ++ii) {
    const int row = m0 + ty * 4 + ii;
    #pragma unroll
    for (int jj = 0; jj < 4; ++jj) {
      const int col = n0 + tx * 4 + jj;
      float d = 0.f;
      #pragma unroll
      for (int r = 0; r < 16; ++r) d += xa[(size_t)row * 16 + r] * B_lora[col * 16 + r];
      out[(size_t)row * N_DIM + col] = c[ii][jj] + 2.0f * d + bias[col] + 2.0f * dbias[col];
    }
  }
}

// ---------------------------------------------------------------------------
extern "C" void kernel_launch(void* const* d_in, const int* in_sizes, int n_in,
                              void* d_out, int out_size, void* d_ws, size_t ws_size,
                              hipStream_t stream) {
  const float* x = (const float*)d_in[0];
  const float* W = (const float*)d_in[1];
  const float* bias = (const float*)d_in[2];
  const float* B_lora = (const float*)d_in[3];
  const float* A_lora = (const float*)d_in[4];
  const float* dbias = (const float*)d_in[5];
  float* out = (float*)d_out;

  const size_t NEED = (size_t)M_DIM * K_DIM * 2 + (size_t)N_DIM * K_DIM * 2;  // 96 MiB
  if (ws_size >= NEED) {
    unsigned short* xb = (unsigned short*)d_ws;
    unsigned short* wb = xb + (size_t)M_DIM * K_DIM;
    cvt_x_kernel<<<2048, 256, 0, stream>>>(x, xb);
    build_wb_kernel<<<dim3(64, 64), 256, 0, stream>>>(W, B_lora, A_lora, wb);
    gemm_kernel<<<(M_DIM / 256) * (N_DIM / 256), 512, 0, stream>>>(xb, wb, bias, dbias, out);
  } else {
    float* xa = (float*)d_ws;
    xa_kernel<<<M_DIM, 256, 0, stream>>>(x, A_lora, xa);
    fgemm_kernel<<<(M_DIM / 64) * (N_DIM / 64), 256, 0, stream>>>(x, W, bias, B_lora, dbias, xa, out);
  }
}

// Round 5
// 545.089 us; speedup vs baseline: 1.1244x; 1.1244x over previous
//
#include <hip/hip_runtime.h>
#include <stdint.h>

#define M_DIM 8192
#define N_DIM 4096
#define K_DIM 4096

typedef __attribute__((ext_vector_type(4))) float f32x4;
typedef __attribute__((ext_vector_type(8))) __bf16 bf16x8;

__device__ __forceinline__ unsigned short f2bf(float f) {
  unsigned int u = __builtin_bit_cast(unsigned int, f);
  u += 0x7FFFu + ((u >> 16) & 1u);   // round-to-nearest-even
  return (unsigned short)(u >> 16);
}

__device__ __forceinline__ void load16_lds(const void* g, void* l) {
  __builtin_amdgcn_global_load_lds(
      (__attribute__((address_space(1))) void*)g,
      (__attribute__((address_space(3))) void*)l,
      16, 0, 0);
}

#define WAITVM(N) asm volatile("s_waitcnt vmcnt(" #N ")" ::: "memory")
#define BARRIER() asm volatile("s_barrier" ::: "memory")

// ---------------------------------------------------------------------------
// Kernel 1: x f32 -> bf16 (vectorized 8 elems/thread)
// ---------------------------------------------------------------------------
__global__ __launch_bounds__(256) void cvt_x_kernel(const float* __restrict__ x,
                                                    unsigned short* __restrict__ xb) {
  const int n8 = (M_DIM * K_DIM) / 8;
  int i = blockIdx.x * blockDim.x + threadIdx.x;
  const int stride = gridDim.x * blockDim.x;
  for (; i < n8; i += stride) {
    const float4* p = (const float4*)x + (size_t)i * 2;
    const float4 a = p[0];
    const float4 b = p[1];
    uint4 o;
    o.x = (unsigned)f2bf(a.x) | ((unsigned)f2bf(a.y) << 16);
    o.y = (unsigned)f2bf(a.z) | ((unsigned)f2bf(a.w) << 16);
    o.z = (unsigned)f2bf(b.x) | ((unsigned)f2bf(b.y) << 16);
    o.w = (unsigned)f2bf(b.z) | ((unsigned)f2bf(b.w) << 16);
    ((uint4*)xb)[i] = o;
  }
}

// ---------------------------------------------------------------------------
// Kernel 2: Wb[o][i] = bf16(W[o][i] + 2 * sum_r B[o][r]*A[r][i])
// ---------------------------------------------------------------------------
__global__ __launch_bounds__(256) void build_wb_kernel(const float* __restrict__ W,
                                                       const float* __restrict__ B_lora,
                                                       const float* __restrict__ A_lora,
                                                       unsigned short* __restrict__ wb) {
  __shared__ float As[64][17];
  __shared__ float Bs[64][17];
  const int t = threadIdx.x;
  const int i0 = blockIdx.x * 64;
  const int o0 = blockIdx.y * 64;
  {
    const int c = t & 63;
    #pragma unroll
    for (int rr = (t >> 6); rr < 16; rr += 4)
      As[c][rr] = A_lora[rr * K_DIM + i0 + c];
    const int r2 = t & 15;
    #pragma unroll
    for (int oo = (t >> 4); oo < 64; oo += 16)
      Bs[oo][r2] = B_lora[(o0 + oo) * 16 + r2];
  }
  __syncthreads();
  const int ci = t & 63;
  const int og = t >> 6;
  float areg[16];
  #pragma unroll
  for (int r = 0; r < 16; ++r) areg[r] = As[ci][r];
  const int i = i0 + ci;
  #pragma unroll 4
  for (int j = 0; j < 16; ++j) {
    const int ol = og * 16 + j;
    float d = 0.f;
    #pragma unroll
    for (int r = 0; r < 16; ++r) d += Bs[ol][r] * areg[r];
    const size_t idx = (size_t)(o0 + ol) * K_DIM + i;
    wb[idx] = f2bf(W[idx] + 2.0f * d);
  }
}

// ---------------------------------------------------------------------------
// Kernel 3: 256x256 bf16 MFMA GEMM, BK=64, 8 waves (2Mx4N).
// out[m][n] = sum_k xb[m][k]*wb[n][k] + bias[n] + 2*dbias[n]
//
// R5 = R3 (proven 307us) + ONE change: fragment ds_reads software-pipelined
// one phase ahead of consumption, with doubled fragment register sets
// (afA/afB, bfA/bfB). Steady-state schedule per tile t (buffer cur):
//   PH1: rd BH1(cur)->bfB  | st A0(t+1) | BAR QUAD(0,0:afA,bfA) VM(2)[A1 t] BAR
//   PH2: rd AH1(cur)->afB  | st B0,B1(t+1) | BAR QUAD(0,1:afA,bfB) VM(4)[A0 t+1] BAR
//   PH3:                      QUAD(1,1:afB,bfB); rd AH0(nxt)->afA; VM(2)[B0 t+1] BAR
//   PH4: st A1(t+1)        | BAR QUAD(1,0:afB,bfA); rd BH0(nxt)->bfA; VM(2)[B1 t+1] BAR
// Every region is vmcnt-retired + barrier-confirmed ONE phase before its
// prefetch read; every read has >=1 MFMA cluster to drain under.
// R3 idioms kept verbatim: asm s_barrier, no explicit lgkmcnt (compiler
// inserts fine-grained waits), read-then-stage issue order, no in-loop branch.
// LDS swizzle/permutation unchanged (R3: 0 bank conflicts).
// ---------------------------------------------------------------------------
__global__ __launch_bounds__(512, 2) void gemm_kernel(const unsigned short* __restrict__ xb,
                                                      const unsigned short* __restrict__ wb,
                                                      const float* __restrict__ bias,
                                                      const float* __restrict__ dbias,
                                                      float* __restrict__ out) {
  constexpr int BK = 64;
  constexpr int NT = K_DIM / BK;                     // 64
  __shared__ char As[65536];                         // 2 x 32KB
  __shared__ char Bs[65536];                         // 2 x 32KB

  const int t = threadIdx.x;
  const int w = t >> 6, l = t & 63;
  const int wr = w >> 2, wc = w & 3;                 // 2M x 4N waves
  constexpr int NBN = N_DIM / 256;                   // 16
  constexpr int NWG = (M_DIM / 256) * NBN;           // 512 (div by 8)
  int bid = (int)blockIdx.x;
  bid = (bid & 7) * (NWG >> 3) + (bid >> 3);         // bijective XCD swizzle
  const int m0 = (bid / NBN) * 256;
  const int n0 = (bid % NBN) * 256;

  // ---- staging constants (per thread) ----
  const int trow = t >> 3;                           // 0..63
  const int scol = ((t & 7) ^ (trow & 7)) * 8;       // inverse-swizzled src chunk
  const int rowoffA[4] = {0, 128, 64, 192};          // slots: A0={0,1} A1={2,3}
  const int ldsoffA[4] = {0, 16384, 8192, 24576};
  const unsigned short* gAp[4];
  #pragma unroll
  for (int j = 0; j < 4; ++j)
    gAp[j] = xb + (size_t)(m0 + rowoffA[j] + trow) * K_DIM + scol;
  const unsigned short* gBp[4];
  #pragma unroll
  for (int j = 0; j < 4; ++j) {
    const int rp = j * 64 + trow;
    const int gr = (rp & 31) + ((rp >> 5) & 3) * 64 + (rp >> 7) * 32;
    gBp[j] = wb + (size_t)(n0 + gr) * K_DIM + scol;
  }
  const int wlds = w * 1024;                         // wave-uniform lane block

  // ---- ds_read constants ----
  const int swz = (l & 7) << 4;
  const int rdk = (l >> 4) * 16;
  const int rdA = (wr * 128 + (l & 15)) * 128;       // A frag base (bytes)
  const int rdB = (wc * 32 + (l & 15)) * 128;        // B frag base (bytes)

  f32x4 acc[8][4];
  #pragma unroll
  for (int i = 0; i < 8; ++i)
    #pragma unroll
    for (int j = 0; j < 4; ++j) acc[i][j] = f32x4{0.f, 0.f, 0.f, 0.f};
  bf16x8 afA[4][2], afB[4][2];   // A-half fragments (AH0 / AH1)
  bf16x8 bfA[2][2], bfB[2][2];   // B-half fragments (BH0 / BH1)

#define STAGE_A(CUR, SLOT, KT) \
  load16_lds(gAp[SLOT] + (KT), As + (CUR) * 32768 + ldsoffA[SLOT] + wlds)
#define STAGE_B(CUR, SLOT, KT) \
  load16_lds(gBp[SLOT] + (KT), Bs + (CUR) * 32768 + (SLOT) * 8192 + wlds)

#define READ_A(CUR, MH, DST)                                                  \
  {                                                                           \
    const char* base_ = As + (CUR) * 32768 + rdA + (MH) * 8192;               \
    _Pragma("unroll") for (int mf_ = 0; mf_ < 4; ++mf_)                       \
      _Pragma("unroll") for (int ks_ = 0; ks_ < 2; ++ks_)                     \
        DST[mf_][ks_] = *(const bf16x8*)(base_ + mf_ * 2048 +                 \
                                         ((ks_ * 64 + rdk) ^ swz));           \
  }
#define READ_B(CUR, NH, DST)                                                  \
  {                                                                           \
    const char* base_ = Bs + (CUR) * 32768 + rdB + (NH) * 16384;              \
    _Pragma("unroll") for (int nf_ = 0; nf_ < 2; ++nf_)                       \
      _Pragma("unroll") for (int ks_ = 0; ks_ < 2; ++ks_)                     \
        DST[nf_][ks_] = *(const bf16x8*)(base_ + nf_ * 2048 +                 \
                                         ((ks_ * 64 + rdk) ^ swz));           \
  }
#define QUAD(MH, NH, AFR, BFR)                                                \
  {                                                                           \
    __builtin_amdgcn_s_setprio(1);                                            \
    _Pragma("unroll") for (int mf_ = 0; mf_ < 4; ++mf_)                       \
      _Pragma("unroll") for (int nf_ = 0; nf_ < 2; ++nf_)                     \
        _Pragma("unroll") for (int ks_ = 0; ks_ < 2; ++ks_)                   \
          acc[(MH) * 4 + mf_][(NH) * 2 + nf_] =                               \
              __builtin_amdgcn_mfma_f32_16x16x32_bf16(                        \
                  AFR[mf_][ks_], BFR[nf_][ks_],                               \
                  acc[(MH) * 4 + mf_][(NH) * 2 + nf_], 0, 0, 0);              \
    __builtin_amdgcn_s_setprio(0);                                            \
  }

  // ---- prologue: stage tile 0; confirm A0,B0,B1; prefetch AH0/BH0 frags ----
  STAGE_A(0, 0, 0); STAGE_A(0, 1, 0);   // A0(0)
  STAGE_B(0, 0, 0); STAGE_B(0, 1, 0);   // B0(0)
  STAGE_B(0, 2, 0); STAGE_B(0, 3, 0);   // B1(0)
  STAGE_A(0, 2, 0); STAGE_A(0, 3, 0);   // A1(0)
  WAITVM(2);   // A0,B0,B1(0) landed; A1(0) in flight
  BARRIER();
  READ_A(0, 0, afA); READ_B(0, 0, bfA);

  int cur = 0;
  for (int kt = 0; kt < NT - 1; ++kt) {
    const int kn = (kt + 1) * BK;
    const int nxt = cur ^ 1;
    // PH1: prefetch BH1(cur); stage A0(t+1); quad(0,0)
    READ_B(cur, 1, bfB);
    STAGE_A(nxt, 0, kn); STAGE_A(nxt, 1, kn);
    BARRIER(); QUAD(0, 0, afA, bfA); WAITVM(2); BARRIER();   // A1(t) landed
    // PH2: prefetch AH1(cur); stage B0,B1(t+1); quad(0,1)
    READ_A(cur, 1, afB);
    STAGE_B(nxt, 0, kn); STAGE_B(nxt, 1, kn);
    STAGE_B(nxt, 2, kn); STAGE_B(nxt, 3, kn);
    BARRIER(); QUAD(0, 1, afA, bfB); WAITVM(4); BARRIER();   // A0(t+1) landed
    // PH3: quad(1,1); cross-tile prefetch AH0(t+1)
    QUAD(1, 1, afB, bfB);
    READ_A(nxt, 0, afA);
    WAITVM(2); BARRIER();                                    // B0(t+1) landed
    // PH4: stage A1(t+1); quad(1,0); cross-tile prefetch BH0(t+1)
    STAGE_A(nxt, 2, kn); STAGE_A(nxt, 3, kn);
    BARRIER(); QUAD(1, 0, afB, bfA);
    READ_B(nxt, 0, bfA);
    WAITVM(2); BARRIER();                                    // B1(t+1) landed
    cur = nxt;
  }
  // ---- final tile: outstanding = A1(last); drain, no staging ----
  READ_B(cur, 1, bfB);
  BARRIER(); QUAD(0, 0, afA, bfA); WAITVM(0); BARRIER();     // A1 landed
  READ_A(cur, 1, afB);
  QUAD(0, 1, afA, bfB);
  QUAD(1, 1, afB, bfB);
  QUAD(1, 0, afB, bfA);

  // ---- epilogue: C/D layout col=l&15, row=4*(l>>4)+j ----
  float bv[4];
  #pragma unroll
  for (int nf = 0; nf < 4; ++nf) {
    const int c = n0 + wc * 64 + nf * 16 + (l & 15);
    bv[nf] = bias[c] + 2.0f * dbias[c];
  }
  #pragma unroll
  for (int mf = 0; mf < 8; ++mf) {
    const int r0 = m0 + wr * 128 + mf * 16 + ((l >> 4) << 2);
    #pragma unroll
    for (int nf = 0; nf < 4; ++nf) {
      const int c = n0 + wc * 64 + nf * 16 + (l & 15);
      const f32x4 v = acc[mf][nf];
      #pragma unroll
      for (int j = 0; j < 4; ++j)
        out[(size_t)(r0 + j) * N_DIM + c] = v[j] + bv[nf];
    }
  }
#undef STAGE_A
#undef STAGE_B
#undef READ_A
#undef READ_B
#undef QUAD
}

// ---------------------------------------------------------------------------
// Fallback path (tiny workspace): xa = x @ A^T, then f32 VALU GEMM + epilogue
// ---------------------------------------------------------------------------
__global__ __launch_bounds__(256) void xa_kernel(const float* __restrict__ x,
                                                 const float* __restrict__ A_lora,
                                                 float* __restrict__ xa) {
  const int m = blockIdx.x;
  const int t = threadIdx.x;
  float acc[16];
  #pragma unroll
  for (int r = 0; r < 16; ++r) acc[r] = 0.f;
  const float* xr = x + (size_t)m * K_DIM;
  for (int k = t; k < K_DIM; k += 256) {
    const float xv = xr[k];
    #pragma unroll
    for (int r = 0; r < 16; ++r) acc[r] += xv * A_lora[r * K_DIM + k];
  }
  __shared__ float red[16][4];
  #pragma unroll
  for (int r = 0; r < 16; ++r) {
    float v = acc[r];
    for (int off = 32; off > 0; off >>= 1) v += __shfl_down(v, off, 64);
    if ((t & 63) == 0) red[r][t >> 6] = v;
  }
  __syncthreads();
  if (t < 16) xa[(size_t)m * 16 + t] = red[t][0] + red[t][1] + red[t][2] + red[t][3];
}

__global__ __launch_bounds__(256) void fgemm_kernel(const float* __restrict__ x,
                                                    const float* __restrict__ W,
                                                    const float* __restrict__ bias,
                                                    const float* __restrict__ B_lora,
                                                    const float* __restrict__ dbias,
                                                    const float* __restrict__ xa,
                                                    float* __restrict__ out) {
  __shared__ float As[64][17];
  __shared__ float Ws[64][17];
  const int t = threadIdx.x;
  const int m0 = (blockIdx.x >> 6) * 64;
  const int n0 = (blockIdx.x & 63) * 64;
  const int tx = t & 15, ty = t >> 4;
  float c[4][4] = {};
  for (int kt = 0; kt < K_DIM; kt += 16) {
    #pragma unroll
    for (int e = 0; e < 4; ++e) {
      const int q = t + e * 256;
      const int r = q >> 4, k = q & 15;
      As[r][k] = x[(size_t)(m0 + r) * K_DIM + kt + k];
      Ws[r][k] = W[(size_t)(n0 + r) * K_DIM + kt + k];
    }
    __syncthreads();
    #pragma unroll
    for (int k = 0; k < 16; ++k) {
      float a[4], b[4];
      #pragma unroll
      for (int ii = 0; ii < 4; ++ii) a[ii] = As[ty * 4 + ii][k];
      #pragma unroll
      for (int jj = 0; jj < 4; ++jj) b[jj] = Ws[tx * 4 + jj][k];
      #pragma unroll
      for (int ii = 0; ii < 4; ++ii)
        #pragma unroll
        for (int jj = 0; jj < 4; ++jj) c[ii][jj] += a[ii] * b[jj];
    }
    __syncthreads();
  }
  #pragma unroll
  for (int ii = 0; ii < 4; ++ii) {
    const int row = m0 + ty * 4 + ii;
    #pragma unroll
    for (int jj = 0; jj < 4; ++jj) {
      const int col = n0 + tx * 4 + jj;
      float d = 0.f;
      #pragma unroll
      for (int r = 0; r < 16; ++r) d += xa[(size_t)row * 16 + r] * B_lora[col * 16 + r];
      out[(size_t)row * N_DIM + col] = c[ii][jj] + 2.0f * d + bias[col] + 2.0f * dbias[col];
    }
  }
}

// ---------------------------------------------------------------------------
extern "C" void kernel_launch(void* const* d_in, const int* in_sizes, int n_in,
                              void* d_out, int out_size, void* d_ws, size_t ws_size,
                              hipStream_t stream) {
  const float* x = (const float*)d_in[0];
  const float* W = (const float*)d_in[1];
  const float* bias = (const float*)d_in[2];
  const float* B_lora = (const float*)d_in[3];
  const float* A_lora = (const float*)d_in[4];
  const float* dbias = (const float*)d_in[5];
  float* out = (float*)d_out;

  const size_t NEED = (size_t)M_DIM * K_DIM * 2 + (size_t)N_DIM * K_DIM * 2;  // 96 MiB
  if (ws_size >= NEED) {
    unsigned short* xb = (unsigned short*)d_ws;
    unsigned short* wb = xb + (size_t)M_DIM * K_DIM;
    cvt_x_kernel<<<2048, 256, 0, stream>>>(x, xb);
    build_wb_kernel<<<dim3(64, 64), 256, 0, stream>>>(W, B_lora, A_lora, wb);
    gemm_kernel<<<(M_DIM / 256) * (N_DIM / 256), 512, 0, stream>>>(xb, wb, bias, dbias, out);
  } else {
    float* xa = (float*)d_ws;
    xa_kernel<<<M_DIM, 256, 0, stream>>>(x, A_lora, xa);
    fgemm_kernel<<<(M_DIM / 64) * (N_DIM / 64), 256, 0, stream>>>(x, W, bias, B_lora, dbias, xa, out);
  }
}

// Round 8
// 535.303 us; speedup vs baseline: 1.1450x; 1.0183x over previous
//
#include <hip/hip_runtime.h>
#include <stdint.h>

#define M_DIM 8192
#define N_DIM 4096
#define K_DIM 4096

typedef __attribute__((ext_vector_type(4))) float f32x4;
typedef __attribute__((ext_vector_type(8))) __bf16 bf16x8;

__device__ __forceinline__ unsigned short f2bf(float f) {
  unsigned int u = __builtin_bit_cast(unsigned int, f);
  u += 0x7FFFu + ((u >> 16) & 1u);   // round-to-nearest-even
  return (unsigned short)(u >> 16);
}

__device__ __forceinline__ void load16_lds(const void* g, void* l) {
  __builtin_amdgcn_global_load_lds(
      (__attribute__((address_space(1))) void*)g,
      (__attribute__((address_space(3))) void*)l,
      16, 0, 0);
}

#define WAITVM(N) asm volatile("s_waitcnt vmcnt(" #N ")" ::: "memory")
#define LGKMH(N)  asm volatile("s_waitcnt lgkmcnt(" #N ")" ::: "memory")
#define BARRIER() __builtin_amdgcn_s_barrier()

// ---------------------------------------------------------------------------
// Kernel 1: x f32 -> bf16 (vectorized 8 elems/thread)
// ---------------------------------------------------------------------------
__global__ __launch_bounds__(256) void cvt_x_kernel(const float* __restrict__ x,
                                                    unsigned short* __restrict__ xb) {
  const int n8 = (M_DIM * K_DIM) / 8;
  int i = blockIdx.x * blockDim.x + threadIdx.x;
  const int stride = gridDim.x * blockDim.x;
  for (; i < n8; i += stride) {
    const float4* p = (const float4*)x + (size_t)i * 2;
    const float4 a = p[0];
    const float4 b = p[1];
    uint4 o;
    o.x = (unsigned)f2bf(a.x) | ((unsigned)f2bf(a.y) << 16);
    o.y = (unsigned)f2bf(a.z) | ((unsigned)f2bf(a.w) << 16);
    o.z = (unsigned)f2bf(b.x) | ((unsigned)f2bf(b.y) << 16);
    o.w = (unsigned)f2bf(b.z) | ((unsigned)f2bf(b.w) << 16);
    ((uint4*)xb)[i] = o;
  }
}

// ---------------------------------------------------------------------------
// Kernel 2: Wb[o][i] = bf16(W[o][i] + 2 * sum_r B[o][r]*A[r][i])
// ---------------------------------------------------------------------------
__global__ __launch_bounds__(256) void build_wb_kernel(const float* __restrict__ W,
                                                       const float* __restrict__ B_lora,
                                                       const float* __restrict__ A_lora,
                                                       unsigned short* __restrict__ wb) {
  __shared__ float As[64][17];
  __shared__ float Bs[64][17];
  const int t = threadIdx.x;
  const int i0 = blockIdx.x * 64;
  const int o0 = blockIdx.y * 64;
  {
    const int c = t & 63;
    #pragma unroll
    for (int rr = (t >> 6); rr < 16; rr += 4)
      As[c][rr] = A_lora[rr * K_DIM + i0 + c];
    const int r2 = t & 15;
    #pragma unroll
    for (int oo = (t >> 4); oo < 64; oo += 16)
      Bs[oo][r2] = B_lora[(o0 + oo) * 16 + r2];
  }
  __syncthreads();
  const int ci = t & 63;
  const int og = t >> 6;
  float areg[16];
  #pragma unroll
  for (int r = 0; r < 16; ++r) areg[r] = As[ci][r];
  const int i = i0 + ci;
  #pragma unroll 4
  for (int j = 0; j < 16; ++j) {
    const int ol = og * 16 + j;
    float d = 0.f;
    #pragma unroll
    for (int r = 0; r < 16; ++r) d += Bs[ol][r] * areg[r];
    const size_t idx = (size_t)(o0 + ol) * K_DIM + i;
    wb[idx] = f2bf(W[idx] + 2.0f * d);
  }
}

// ---------------------------------------------------------------------------
// Kernel 3: 256x256 bf16 MFMA GEMM, BK=64, 8 waves (2Mx4N).
// out[m][n] = sum_k xb[m][k]*wb[n][k] + bias[n] + 2*dbias[n]
//
// R6/R7/R8: FAITHFUL m201 8-phase port. Per K-tile t (buffer b=t&1), 4
// phases, quadrant order (0,0)->(1,0)->(1,1)->(0,1); each phase:
//   {ds_read subtile; stage 1 half-tile (2 loads); [lgkm(8) if 12 reads];
//    BARRIER; lgkm(0); setprio1; 16 MFMA; setprio0; BARRIER}
// Stage cadence: BH1(t+1)@ph1, AH0(t+2)@ph2, BH0(t+2)@ph3, AH1(t+2)@ph4.
// vmcnt(6) ONCE per K-tile at ph4 (2 loads x 3 half-tiles outstanding);
// ledger: at ph4(t) queue=[tile t+1 (8 loads), AH0/BH0/AH1(t+2) (6)] ->
// vmcnt(6) retires exactly tile t+1. Region-free proof: each staged region's
// last read is >=1 closing barrier before the stage issue.
// Peeled final 2 tiles (no in-loop branch): t=62 stages BH1(63) only, ph4
// waits vmcnt(0); t=63 reads+QUADs only.
// LDS layout/swizzle unchanged from R3 (verified 0 bank conflicts):
// A linear byte=gr*128 via slot map, B row-permuted, XOR (row&7)<<4.
// ---------------------------------------------------------------------------
__global__ __launch_bounds__(512, 2) void gemm_kernel(const unsigned short* __restrict__ xb,
                                                      const unsigned short* __restrict__ wb,
                                                      const float* __restrict__ bias,
                                                      const float* __restrict__ dbias,
                                                      float* __restrict__ out) {
  constexpr int BK = 64;
  constexpr int NT = K_DIM / BK;                     // 64
  __shared__ char As[65536];                         // 2 x 32KB
  __shared__ char Bs[65536];                         // 2 x 32KB

  const int t = threadIdx.x;
  const int w = t >> 6, l = t & 63;
  const int wr = w >> 2, wc = w & 3;                 // 2M x 4N waves
  constexpr int NBN = N_DIM / 256;                   // 16
  constexpr int NWG = (M_DIM / 256) * NBN;           // 512 (div by 8)
  int bid = (int)blockIdx.x;
  bid = (bid & 7) * (NWG >> 3) + (bid >> 3);         // bijective XCD swizzle
  const int m0 = (bid / NBN) * 256;
  const int n0 = (bid % NBN) * 256;

  // ---- staging constants (per thread) ----
  const int trow = t >> 3;                           // 0..63
  const int scol = ((t & 7) ^ (trow & 7)) * 8;       // inverse-swizzled src chunk
  const int rowoffA[4] = {0, 128, 64, 192};          // slots: AH0={0,1} AH1={2,3}
  const int ldsoffA[4] = {0, 16384, 8192, 24576};
  const unsigned short* gAp[4];
  #pragma unroll
  for (int j = 0; j < 4; ++j)
    gAp[j] = xb + (size_t)(m0 + rowoffA[j] + trow) * K_DIM + scol;
  const unsigned short* gBp[4];
  #pragma unroll
  for (int j = 0; j < 4; ++j) {
    const int rp = j * 64 + trow;
    const int gr = (rp & 31) + ((rp >> 5) & 3) * 64 + (rp >> 7) * 32;
    gBp[j] = wb + (size_t)(n0 + gr) * K_DIM + scol;
  }
  const int wlds = w * 1024;                         // wave-uniform lane block

  // ---- ds_read constants ----
  const int swz = (l & 7) << 4;
  const int rdk = (l >> 4) * 16;
  const int rdA = (wr * 128 + (l & 15)) * 128;       // A frag base (bytes)
  const int rdB = (wc * 32 + (l & 15)) * 128;        // B frag base (bytes)

  f32x4 acc[8][4];
  #pragma unroll
  for (int i = 0; i < 8; ++i)
    #pragma unroll
    for (int j = 0; j < 4; ++j) acc[i][j] = f32x4{0.f, 0.f, 0.f, 0.f};
  bf16x8 afA[4][2], afB[4][2];   // A halves: afA=AH0, afB=AH1
  bf16x8 bfA[2][2], bfB[2][2];   // B halves: bfA=BH0, bfB=BH1

#define STAGE_A(CUR, SLOT, KT) \
  load16_lds(gAp[SLOT] + (KT), As + (CUR) * 32768 + ldsoffA[SLOT] + wlds)
#define STAGE_B(CUR, SLOT, KT) \
  load16_lds(gBp[SLOT] + (KT), Bs + (CUR) * 32768 + (SLOT) * 8192 + wlds)

#define READ_A(CUR, MH, DST)                                                  \
  {                                                                           \
    const char* base_ = As + (CUR) * 32768 + rdA + (MH) * 8192;               \
    _Pragma("unroll") for (int mf_ = 0; mf_ < 4; ++mf_)                       \
      _Pragma("unroll") for (int ks_ = 0; ks_ < 2; ++ks_)                     \
        DST[mf_][ks_] = *(const bf16x8*)(base_ + mf_ * 2048 +                 \
                                         ((ks_ * 64 + rdk) ^ swz));           \
  }
#define READ_B(CUR, NH, DST)                                                  \
  {                                                                           \
    const char* base_ = Bs + (CUR) * 32768 + rdB + (NH) * 16384;              \
    _Pragma("unroll") for (int nf_ = 0; nf_ < 2; ++nf_)                       \
      _Pragma("unroll") for (int ks_ = 0; ks_ < 2; ++ks_)                     \
        DST[nf_][ks_] = *(const bf16x8*)(base_ + nf_ * 2048 +                 \
                                         ((ks_ * 64 + rdk) ^ swz));           \
  }
#define QUAD(MH, NH, AFR, BFR)                                                \
  {                                                                           \
    __builtin_amdgcn_s_setprio(1);                                            \
    _Pragma("unroll") for (int mf_ = 0; mf_ < 4; ++mf_)                       \
      _Pragma("unroll") for (int nf_ = 0; nf_ < 2; ++nf_)                     \
        _Pragma("unroll") for (int ks_ = 0; ks_ < 2; ++ks_)                   \
          acc[(MH) * 4 + mf_][(NH) * 2 + nf_] =                               \
              __builtin_amdgcn_mfma_f32_16x16x32_bf16(                        \
                  AFR[mf_][ks_], BFR[nf_][ks_],                               \
                  acc[(MH) * 4 + mf_][(NH) * 2 + nf_], 0, 0, 0);              \
    __builtin_amdgcn_s_setprio(0);                                            \
  }

  // ---- prologue: tile0 fully + AH0,BH0,AH1 of tile1 (BH1(1) staged @ph1(0))
  STAGE_A(0, 0, 0); STAGE_A(0, 1, 0);    // AH0(0)
  STAGE_B(0, 0, 0); STAGE_B(0, 1, 0);    // BH0(0)
  STAGE_A(0, 2, 0); STAGE_A(0, 3, 0);    // AH1(0)
  STAGE_B(0, 2, 0); STAGE_B(0, 3, 0);    // BH1(0)
  STAGE_A(1, 0, BK); STAGE_A(1, 1, BK);  // AH0(1)
  STAGE_B(1, 0, BK); STAGE_B(1, 1, BK);  // BH0(1)
  STAGE_A(1, 2, BK); STAGE_A(1, 3, BK);  // AH1(1)
  WAITVM(6);   // tile0 landed; AH0/BH0/AH1(1) in flight
  BARRIER();

  for (int kt = 0; kt < NT - 2; ++kt) {
    const int b = kt & 1;
    const int k1 = (kt + 1) * BK;
    const int k2 = (kt + 2) * BK;
    // PH1: read AH0,BH0 (12); stage BH1(t+1); quad (0,0)
    READ_A(b, 0, afA); READ_B(b, 0, bfA);
    STAGE_B(b ^ 1, 2, k1); STAGE_B(b ^ 1, 3, k1);
    LGKMH(8);
    BARRIER(); LGKMH(0); QUAD(0, 0, afA, bfA); BARRIER();
    // PH2: read AH1 (8); stage AH0(t+2); quad (1,0)
    READ_A(b, 1, afB);
    STAGE_A(b, 0, k2); STAGE_A(b, 1, k2);
    BARRIER(); LGKMH(0); QUAD(1, 0, afB, bfA); BARRIER();
    // PH3: read BH1 (4); stage BH0(t+2); quad (1,1)
    READ_B(b, 1, bfB);
    STAGE_B(b, 0, k2); STAGE_B(b, 1, k2);
    BARRIER(); LGKMH(0); QUAD(1, 1, afB, bfB); BARRIER();
    // PH4: stage AH1(t+2); vmcnt(6) -> tile t+1 landed; quad (0,1)
    STAGE_A(b, 2, k2); STAGE_A(b, 3, k2);
    WAITVM(6);
    BARRIER(); QUAD(0, 1, afA, bfB); BARRIER();
  }
  // ---- peeled tile NT-2 (buf 0): stage only BH1(NT-1); drain to 0 ----
  {
    const int k1 = (NT - 1) * BK;
    READ_A(0, 0, afA); READ_B(0, 0, bfA);
    STAGE_B(1, 2, k1); STAGE_B(1, 3, k1);
    LGKMH(8);
    BARRIER(); LGKMH(0); QUAD(0, 0, afA, bfA); BARRIER();
    READ_A(0, 1, afB);
    BARRIER(); LGKMH(0); QUAD(1, 0, afB, bfA); BARRIER();
    READ_B(0, 1, bfB);
    BARRIER(); LGKMH(0); QUAD(1, 1, afB, bfB); BARRIER();
    WAITVM(0);
    BARRIER(); QUAD(0, 1, afA, bfB); BARRIER();
  }
  // ---- peeled tile NT-1 (buf 1): reads only, no stages/waits/barriers ----
  READ_A(1, 0, afA); READ_B(1, 0, bfA);
  QUAD(0, 0, afA, bfA);
  READ_A(1, 1, afB);
  QUAD(1, 0, afB, bfA);
  READ_B(1, 1, bfB);
  QUAD(1, 1, afB, bfB);
  QUAD(0, 1, afA, bfB);

  // ---- epilogue: C/D layout col=l&15, row=4*(l>>4)+j ----
  float bv[4];
  #pragma unroll
  for (int nf = 0; nf < 4; ++nf) {
    const int c = n0 + wc * 64 + nf * 16 + (l & 15);
    bv[nf] = bias[c] + 2.0f * dbias[c];
  }
  #pragma unroll
  for (int mf = 0; mf < 8; ++mf) {
    const int r0 = m0 + wr * 128 + mf * 16 + ((l >> 4) << 2);
    #pragma unroll
    for (int nf = 0; nf < 4; ++nf) {
      const int c = n0 + wc * 64 + nf * 16 + (l & 15);
      const f32x4 v = acc[mf][nf];
      #pragma unroll
      for (int j = 0; j < 4; ++j)
        out[(size_t)(r0 + j) * N_DIM + c] = v[j] + bv[nf];
    }
  }
#undef STAGE_A
#undef STAGE_B
#undef READ_A
#undef READ_B
#undef QUAD
}

// ---------------------------------------------------------------------------
// Fallback path (tiny workspace): xa = x @ A^T, then f32 VALU GEMM + epilogue
// ---------------------------------------------------------------------------
__global__ __launch_bounds__(256) void xa_kernel(const float* __restrict__ x,
                                                 const float* __restrict__ A_lora,
                                                 float* __restrict__ xa) {
  const int m = blockIdx.x;
  const int t = threadIdx.x;
  float acc[16];
  #pragma unroll
  for (int r = 0; r < 16; ++r) acc[r] = 0.f;
  const float* xr = x + (size_t)m * K_DIM;
  for (int k = t; k < K_DIM; k += 256) {
    const float xv = xr[k];
    #pragma unroll
    for (int r = 0; r < 16; ++r) acc[r] += xv * A_lora[r * K_DIM + k];
  }
  __shared__ float red[16][4];
  #pragma unroll
  for (int r = 0; r < 16; ++r) {
    float v = acc[r];
    for (int off = 32; off > 0; off >>= 1) v += __shfl_down(v, off, 64);
    if ((t & 63) == 0) red[r][t >> 6] = v;
  }
  __syncthreads();
  if (t < 16) xa[(size_t)m * 16 + t] = red[t][0] + red[t][1] + red[t][2] + red[t][3];
}

__global__ __launch_bounds__(256) void fgemm_kernel(const float* __restrict__ x,
                                                    const float* __restrict__ W,
                                                    const float* __restrict__ bias,
                                                    const float* __restrict__ B_lora,
                                                    const float* __restrict__ dbias,
                                                    const float* __restrict__ xa,
                                                    float* __restrict__ out) {
  __shared__ float As[64][17];
  __shared__ float Ws[64][17];
  const int t = threadIdx.x;
  const int m0 = (blockIdx.x >> 6) * 64;
  const int n0 = (blockIdx.x & 63) * 64;
  const int tx = t & 15, ty = t >> 4;
  float c[4][4] = {};
  for (int kt = 0; kt < K_DIM; kt += 16) {
    #pragma unroll
    for (int e = 0; e < 4; ++e) {
      const int q = t + e * 256;
      const int r = q >> 4, k = q & 15;
      As[r][k] = x[(size_t)(m0 + r) * K_DIM + kt + k];
      Ws[r][k] = W[(size_t)(n0 + r) * K_DIM + kt + k];
    }
    __syncthreads();
    #pragma unroll
    for (int k = 0; k < 16; ++k) {
      float a[4], b[4];
      #pragma unroll
      for (int ii = 0; ii < 4; ++ii) a[ii] = As[ty * 4 + ii][k];
      #pragma unroll
      for (int jj = 0; jj < 4; ++jj) b[jj] = Ws[tx * 4 + jj][k];
      #pragma unroll
      for (int ii = 0; ii < 4; ++ii)
        #pragma unroll
        for (int jj = 0; jj < 4; ++jj) c[ii][jj] += a[ii] * b[jj];
    }
    __syncthreads();
  }
  #pragma unroll
  for (int ii = 0; ii < 4; ++ii) {
    const int row = m0 + ty * 4 + ii;
    #pragma unroll
    for (int jj = 0; jj < 4; ++jj) {
      const int col = n0 + tx * 4 + jj;
      float d = 0.f;
      #pragma unroll
      for (int r = 0; r < 16; ++r) d += xa[(size_t)row * 16 + r] * B_lora[col * 16 + r];
      out[(size_t)row * N_DIM + col] = c[ii][jj] + 2.0f * d + bias[col] + 2.0f * dbias[col];
    }
  }
}

// ---------------------------------------------------------------------------
extern "C" void kernel_launch(void* const* d_in, const int* in_sizes, int n_in,
                              void* d_out, int out_size, void* d_ws, size_t ws_size,
                              hipStream_t stream) {
  const float* x = (const float*)d_in[0];
  const float* W = (const float*)d_in[1];
  const float* bias = (const float*)d_in[2];
  const float* B_lora = (const float*)d_in[3];
  const float* A_lora = (const float*)d_in[4];
  const float* dbias = (const float*)d_in[5];
  float* out = (float*)d_out;

  const size_t NEED = (size_t)M_DIM * K_DIM * 2 + (size_t)N_DIM * K_DIM * 2;  // 96 MiB
  if (ws_size >= NEED) {
    unsigned short* xb = (unsigned short*)d_ws;
    unsigned short* wb = xb + (size_t)M_DIM * K_DIM;
    cvt_x_kernel<<<2048, 256, 0, stream>>>(x, xb);
    build_wb_kernel<<<dim3(64, 64), 256, 0, stream>>>(W, B_lora, A_lora, wb);
    gemm_kernel<<<(M_DIM / 256) * (N_DIM / 256), 512, 0, stream>>>(xb, wb, bias, dbias, out);
  } else {
    float* xa = (float*)d_ws;
    xa_kernel<<<M_DIM, 256, 0, stream>>>(x, A_lora, xa);
    fgemm_kernel<<<(M_DIM / 64) * (N_DIM / 64), 256, 0, stream>>>(x, W, bias, B_lora, dbias, xa, out);
  }
}

// Round 11
// 534.597 us; speedup vs baseline: 1.1465x; 1.0013x over previous
//
#include <hip/hip_runtime.h>
#include <stdint.h>

#define M_DIM 8192
#define N_DIM 4096
#define K_DIM 4096

typedef __attribute__((ext_vector_type(4))) float f32x4;
typedef __attribute__((ext_vector_type(8))) __bf16 bf16x8;

__device__ __forceinline__ unsigned short f2bf(float f) {
  unsigned int u = __builtin_bit_cast(unsigned int, f);
  u += 0x7FFFu + ((u >> 16) & 1u);   // round-to-nearest-even
  return (unsigned short)(u >> 16);
}

__device__ __forceinline__ void load16_lds(const void* g, void* l) {
  __builtin_amdgcn_global_load_lds(
      (__attribute__((address_space(1))) void*)g,
      (__attribute__((address_space(3))) void*)l,
      16, 0, 0);
}

#define WAITVM(N) asm volatile("s_waitcnt vmcnt(" #N ")" ::: "memory")
#define LGKMH(N)  asm volatile("s_waitcnt lgkmcnt(" #N ")" ::: "memory")
#define BARRIER() __builtin_amdgcn_s_barrier()

// ---------------------------------------------------------------------------
// Kernel 1: x f32 -> bf16 (vectorized 8 elems/thread)
// ---------------------------------------------------------------------------
__global__ __launch_bounds__(256) void cvt_x_kernel(const float* __restrict__ x,
                                                    unsigned short* __restrict__ xb) {
  const int n8 = (M_DIM * K_DIM) / 8;
  int i = blockIdx.x * blockDim.x + threadIdx.x;
  const int stride = gridDim.x * blockDim.x;
  for (; i < n8; i += stride) {
    const float4* p = (const float4*)x + (size_t)i * 2;
    const float4 a = p[0];
    const float4 b = p[1];
    uint4 o;
    o.x = (unsigned)f2bf(a.x) | ((unsigned)f2bf(a.y) << 16);
    o.y = (unsigned)f2bf(a.z) | ((unsigned)f2bf(a.w) << 16);
    o.z = (unsigned)f2bf(b.x) | ((unsigned)f2bf(b.y) << 16);
    o.w = (unsigned)f2bf(b.z) | ((unsigned)f2bf(b.w) << 16);
    ((uint4*)xb)[i] = o;
  }
}

// ---------------------------------------------------------------------------
// Kernel 2: Wb[o][i] = bf16(W[o][i] + 2 * sum_r B[o][r]*A[r][i])
// ---------------------------------------------------------------------------
__global__ __launch_bounds__(256) void build_wb_kernel(const float* __restrict__ W,
                                                       const float* __restrict__ B_lora,
                                                       const float* __restrict__ A_lora,
                                                       unsigned short* __restrict__ wb) {
  __shared__ float As[64][17];
  __shared__ float Bs[64][17];
  const int t = threadIdx.x;
  const int i0 = blockIdx.x * 64;
  const int o0 = blockIdx.y * 64;
  {
    const int c = t & 63;
    #pragma unroll
    for (int rr = (t >> 6); rr < 16; rr += 4)
      As[c][rr] = A_lora[rr * K_DIM + i0 + c];
    const int r2 = t & 15;
    #pragma unroll
    for (int oo = (t >> 4); oo < 64; oo += 16)
      Bs[oo][r2] = B_lora[(o0 + oo) * 16 + r2];
  }
  __syncthreads();
  const int ci = t & 63;
  const int og = t >> 6;
  float areg[16];
  #pragma unroll
  for (int r = 0; r < 16; ++r) areg[r] = As[ci][r];
  const int i = i0 + ci;
  #pragma unroll 4
  for (int j = 0; j < 16; ++j) {
    const int ol = og * 16 + j;
    float d = 0.f;
    #pragma unroll
    for (int r = 0; r < 16; ++r) d += Bs[ol][r] * areg[r];
    const size_t idx = (size_t)(o0 + ol) * K_DIM + i;
    wb[idx] = f2bf(W[idx] + 2.0f * d);
  }
}

// ---------------------------------------------------------------------------
// Kernel 3: 256x256 bf16 MFMA GEMM, BK=64, 8 waves (2Mx4N).
// out[m][n] = sum_k xb[m][k]*wb[n][k] + bias[n] + 2*dbias[n]
//
// R9/R10/R11 = R8 (270us, MfmaUtil 45.8%) + two targeted changes:
//  (1) main loop unrolled x2 with LITERAL buffer index (m201's 8-phase/2-tile
//      iter form) -> all LDS offsets compile-time; kills runtime-b VALU.
//  (2) read rebalance 12/8/4/0 -> 8/8/4/4: BH0's 4 reads move to ph4 of the
//      PREVIOUS tile, after WAITVM(6)+BARRIER (tile t+1 confirmed landed),
//      issued before QUAD(0,1) so they drain under its MFMA cluster.
//      bfA registers are dead after ph2; BH0(t+2) stage issues later (ph3(t)).
//      LGKMH(8) hint dropped (no 12-read phase).
// Stage cadence and vmcnt ledger UNCHANGED from R8 (verified):
//   B1(t+1)@ph1, A0(t+2)@ph2, B0(t+2)@ph3, A1(t+2)@ph4; WAITVM(6)@ph4
//   retires tile t+1 (14 outstanding -> 6). Tile62: WAITVM(0). Tile63: pure.
// LDS layout/swizzle unchanged (0 bank conflicts measured).
// ---------------------------------------------------------------------------
__global__ __launch_bounds__(512, 2) void gemm_kernel(const unsigned short* __restrict__ xb,
                                                      const unsigned short* __restrict__ wb,
                                                      const float* __restrict__ bias,
                                                      const float* __restrict__ dbias,
                                                      float* __restrict__ out) {
  constexpr int BK = 64;
  constexpr int NT = K_DIM / BK;                     // 64
  __shared__ char As[65536];                         // 2 x 32KB
  __shared__ char Bs[65536];                         // 2 x 32KB

  const int t = threadIdx.x;
  const int w = t >> 6, l = t & 63;
  const int wr = w >> 2, wc = w & 3;                 // 2M x 4N waves
  constexpr int NBN = N_DIM / 256;                   // 16
  constexpr int NWG = (M_DIM / 256) * NBN;           // 512 (div by 8)
  int bid = (int)blockIdx.x;
  bid = (bid & 7) * (NWG >> 3) + (bid >> 3);         // bijective XCD swizzle
  const int m0 = (bid / NBN) * 256;
  const int n0 = (bid % NBN) * 256;

  // ---- staging constants (per thread) ----
  const int trow = t >> 3;                           // 0..63
  const int scol = ((t & 7) ^ (trow & 7)) * 8;       // inverse-swizzled src chunk
  const int rowoffA[4] = {0, 128, 64, 192};          // slots: AH0={0,1} AH1={2,3}
  const int ldsoffA[4] = {0, 16384, 8192, 24576};
  const unsigned short* gAp[4];
  #pragma unroll
  for (int j = 0; j < 4; ++j)
    gAp[j] = xb + (size_t)(m0 + rowoffA[j] + trow) * K_DIM + scol;
  const unsigned short* gBp[4];
  #pragma unroll
  for (int j = 0; j < 4; ++j) {
    const int rp = j * 64 + trow;
    const int gr = (rp & 31) + ((rp >> 5) & 3) * 64 + (rp >> 7) * 32;
    gBp[j] = wb + (size_t)(n0 + gr) * K_DIM + scol;
  }
  const int wlds = w * 1024;                         // wave-uniform lane block

  // ---- ds_read constants ----
  const int swz = (l & 7) << 4;
  const int rdk = (l >> 4) * 16;
  const int rdA = (wr * 128 + (l & 15)) * 128;       // A frag base (bytes)
  const int rdB = (wc * 32 + (l & 15)) * 128;        // B frag base (bytes)

  f32x4 acc[8][4];
  #pragma unroll
  for (int i = 0; i < 8; ++i)
    #pragma unroll
    for (int j = 0; j < 4; ++j) acc[i][j] = f32x4{0.f, 0.f, 0.f, 0.f};
  bf16x8 afA[4][2], afB[4][2];   // A halves: afA=AH0, afB=AH1
  bf16x8 bfA[2][2], bfB[2][2];   // B halves: bfA=BH0, bfB=BH1

#define STAGE_A(CUR, SLOT, KT) \
  load16_lds(gAp[SLOT] + (KT), As + (CUR) * 32768 + ldsoffA[SLOT] + wlds)
#define STAGE_B(CUR, SLOT, KT) \
  load16_lds(gBp[SLOT] + (KT), Bs + (CUR) * 32768 + (SLOT) * 8192 + wlds)

#define READ_A(CUR, MH, DST)                                                  \
  {                                                                           \
    const char* base_ = As + (CUR) * 32768 + rdA + (MH) * 8192;               \
    _Pragma("unroll") for (int mf_ = 0; mf_ < 4; ++mf_)                       \
      _Pragma("unroll") for (int ks_ = 0; ks_ < 2; ++ks_)                     \
        DST[mf_][ks_] = *(const bf16x8*)(base_ + mf_ * 2048 +                 \
                                         ((ks_ * 64 + rdk) ^ swz));           \
  }
#define READ_B(CUR, NH, DST)                                                  \
  {                                                                           \
    const char* base_ = Bs + (CUR) * 32768 + rdB + (NH) * 16384;              \
    _Pragma("unroll") for (int nf_ = 0; nf_ < 2; ++nf_)                       \
      _Pragma("unroll") for (int ks_ = 0; ks_ < 2; ++ks_)                     \
        DST[nf_][ks_] = *(const bf16x8*)(base_ + nf_ * 2048 +                 \
                                         ((ks_ * 64 + rdk) ^ swz));           \
  }
#define QUAD(MH, NH, AFR, BFR)                                                \
  {                                                                           \
    __builtin_amdgcn_s_setprio(1);                                            \
    _Pragma("unroll") for (int mf_ = 0; mf_ < 4; ++mf_)                       \
      _Pragma("unroll") for (int nf_ = 0; nf_ < 2; ++nf_)                     \
        _Pragma("unroll") for (int ks_ = 0; ks_ < 2; ++ks_)                   \
          acc[(MH) * 4 + mf_][(NH) * 2 + nf_] =                               \
              __builtin_amdgcn_mfma_f32_16x16x32_bf16(                        \
                  AFR[mf_][ks_], BFR[nf_][ks_],                               \
                  acc[(MH) * 4 + mf_][(NH) * 2 + nf_], 0, 0, 0);              \
    __builtin_amdgcn_s_setprio(0);                                            \
  }

// One K-tile, literal buffer index B (compile-time LDS offsets).
// Phases: 8/8/4/4 reads; stage 1 half-tile each; vmcnt(6) once at ph4.
#define TILE_BODY(B, KT)                                                      \
  {                                                                           \
    const int k1_ = ((KT) + 1) * BK;                                          \
    const int k2_ = ((KT) + 2) * BK;                                          \
    /* PH1: read AH0(8); stage BH1(t+1); quad (0,0) */                        \
    READ_A(B, 0, afA);                                                        \
    STAGE_B((B) ^ 1, 2, k1_); STAGE_B((B) ^ 1, 3, k1_);                       \
    BARRIER(); LGKMH(0); QUAD(0, 0, afA, bfA); BARRIER();                     \
    /* PH2: read AH1(8); stage AH0(t+2); quad (1,0) */                        \
    READ_A(B, 1, afB);                                                        \
    STAGE_A(B, 0, k2_); STAGE_A(B, 1, k2_);                                   \
    BARRIER(); LGKMH(0); QUAD(1, 0, afB, bfA); BARRIER();                     \
    /* PH3: read BH1(4); stage BH0(t+2); quad (1,1) */                        \
    READ_B(B, 1, bfB);                                                        \
    STAGE_B(B, 0, k2_); STAGE_B(B, 1, k2_);                                   \
    BARRIER(); LGKMH(0); QUAD(1, 1, afB, bfB); BARRIER();                     \
    /* PH4: stage AH1(t+2); vmcnt(6) -> tile t+1 landed; read BH0(t+1,4) */   \
    /*      under quad (0,1) */                                               \
    STAGE_A(B, 2, k2_); STAGE_A(B, 3, k2_);                                   \
    WAITVM(6);                                                                \
    BARRIER();                                                                \
    READ_B((B) ^ 1, 0, bfA);                                                  \
    QUAD(0, 1, afA, bfB); BARRIER();                                          \
  }

  // ---- prologue: tile0 fully + AH0,BH0,AH1 of tile1; prefetch bfA(0) ----
  STAGE_A(0, 0, 0); STAGE_A(0, 1, 0);    // AH0(0)
  STAGE_B(0, 0, 0); STAGE_B(0, 1, 0);    // BH0(0)
  STAGE_A(0, 2, 0); STAGE_A(0, 3, 0);    // AH1(0)
  STAGE_B(0, 2, 0); STAGE_B(0, 3, 0);    // BH1(0)
  STAGE_A(1, 0, BK); STAGE_A(1, 1, BK);  // AH0(1)
  STAGE_B(1, 0, BK); STAGE_B(1, 1, BK);  // BH0(1)
  STAGE_A(1, 2, BK); STAGE_A(1, 3, BK);  // AH1(1)
  WAITVM(6);   // tile0 landed; AH0/BH0/AH1(1) in flight
  BARRIER();
  READ_B(0, 0, bfA);

  for (int kt = 0; kt < NT - 2; kt += 2) {
    TILE_BODY(0, kt);
    TILE_BODY(1, kt + 1);
  }
  // ---- peeled tile NT-2=62 (buf 0): stage only BH1(63); drain to 0 ----
  {
    const int k1 = (NT - 1) * BK;
    READ_A(0, 0, afA);
    STAGE_B(1, 2, k1); STAGE_B(1, 3, k1);
    BARRIER(); LGKMH(0); QUAD(0, 0, afA, bfA); BARRIER();
    READ_A(0, 1, afB);
    BARRIER(); LGKMH(0); QUAD(1, 0, afB, bfA); BARRIER();
    READ_B(0, 1, bfB);
    BARRIER(); LGKMH(0); QUAD(1, 1, afB, bfB); BARRIER();
    WAITVM(0);
    BARRIER();
    READ_B(1, 0, bfA);
    QUAD(0, 1, afA, bfB); BARRIER();
  }
  // ---- peeled tile NT-1=63 (buf 1): reads only (no stages in flight) ----
  READ_A(1, 0, afA);
  LGKMH(0); QUAD(0, 0, afA, bfA);
  READ_A(1, 1, afB);
  LGKMH(0); QUAD(1, 0, afB, bfA);
  READ_B(1, 1, bfB);
  LGKMH(0); QUAD(1, 1, afB, bfB);
  QUAD(0, 1, afA, bfB);

  // ---- epilogue: C/D layout col=l&15, row=4*(l>>4)+j ----
  float bv[4];
  #pragma unroll
  for (int nf = 0; nf < 4; ++nf) {
    const int c = n0 + wc * 64 + nf * 16 + (l & 15);
    bv[nf] = bias[c] + 2.0f * dbias[c];
  }
  #pragma unroll
  for (int mf = 0; mf < 8; ++mf) {
    const int r0 = m0 + wr * 128 + mf * 16 + ((l >> 4) << 2);
    #pragma unroll
    for (int nf = 0; nf < 4; ++nf) {
      const int c = n0 + wc * 64 + nf * 16 + (l & 15);
      const f32x4 v = acc[mf][nf];
      #pragma unroll
      for (int j = 0; j < 4; ++j)
        out[(size_t)(r0 + j) * N_DIM + c] = v[j] + bv[nf];
    }
  }
#undef TILE_BODY
#undef STAGE_A
#undef STAGE_B
#undef READ_A
#undef READ_B
#undef QUAD
}

// ---------------------------------------------------------------------------
// Fallback path (tiny workspace): xa = x @ A^T, then f32 VALU GEMM + epilogue
// ---------------------------------------------------------------------------
__global__ __launch_bounds__(256) void xa_kernel(const float* __restrict__ x,
                                                 const float* __restrict__ A_lora,
                                                 float* __restrict__ xa) {
  const int m = blockIdx.x;
  const int t = threadIdx.x;
  float acc[16];
  #pragma unroll
  for (int r = 0; r < 16; ++r) acc[r] = 0.f;
  const float* xr = x + (size_t)m * K_DIM;
  for (int k = t; k < K_DIM; k += 256) {
    const float xv = xr[k];
    #pragma unroll
    for (int r = 0; r < 16; ++r) acc[r] += xv * A_lora[r * K_DIM + k];
  }
  __shared__ float red[16][4];
  #pragma unroll
  for (int r = 0; r < 16; ++r) {
    float v = acc[r];
    for (int off = 32; off > 0; off >>= 1) v += __shfl_down(v, off, 64);
    if ((t & 63) == 0) red[r][t >> 6] = v;
  }
  __syncthreads();
  if (t < 16) xa[(size_t)m * 16 + t] = red[t][0] + red[t][1] + red[t][2] + red[t][3];
}

__global__ __launch_bounds__(256) void fgemm_kernel(const float* __restrict__ x,
                                                    const float* __restrict__ W,
                                                    const float* __restrict__ bias,
                                                    const float* __restrict__ B_lora,
                                                    const float* __restrict__ dbias,
                                                    const float* __restrict__ xa,
                                                    float* __restrict__ out) {
  __shared__ float As[64][17];
  __shared__ float Ws[64][17];
  const int t = threadIdx.x;
  const int m0 = (blockIdx.x >> 6) * 64;
  const int n0 = (blockIdx.x & 63) * 64;
  const int tx = t & 15, ty = t >> 4;
  float c[4][4] = {};
  for (int kt = 0; kt < K_DIM; kt += 16) {
    #pragma unroll
    for (int e = 0; e < 4; ++e) {
      const int q = t + e * 256;
      const int r = q >> 4, k = q & 15;
      As[r][k] = x[(size_t)(m0 + r) * K_DIM + kt + k];
      Ws[r][k] = W[(size_t)(n0 + r) * K_DIM + kt + k];
    }
    __syncthreads();
    #pragma unroll
    for (int k = 0; k < 16; ++k) {
      float a[4], b[4];
      #pragma unroll
      for (int ii = 0; ii < 4; ++ii) a[ii] = As[ty * 4 + ii][k];
      #pragma unroll
      for (int jj = 0; jj < 4; ++jj) b[jj] = Ws[tx * 4 + jj][k];
      #pragma unroll
      for (int ii = 0; ii < 4; ++ii)
        #pragma unroll
        for (int jj = 0; jj < 4; ++jj) c[ii][jj] += a[ii] * b[jj];
    }
    __syncthreads();
  }
  #pragma unroll
  for (int ii = 0; ii < 4; ++ii) {
    const int row = m0 + ty * 4 + ii;
    #pragma unroll
    for (int jj = 0; jj < 4; ++jj) {
      const int col = n0 + tx * 4 + jj;
      float d = 0.f;
      #pragma unroll
      for (int r = 0; r < 16; ++r) d += xa[(size_t)row * 16 + r] * B_lora[col * 16 + r];
      out[(size_t)row * N_DIM + col] = c[ii][jj] + 2.0f * d + bias[col] + 2.0f * dbias[col];
    }
  }
}

// ---------------------------------------------------------------------------
extern "C" void kernel_launch(void* const* d_in, const int* in_sizes, int n_in,
                              void* d_out, int out_size, void* d_ws, size_t ws_size,
                              hipStream_t stream) {
  const float* x = (const float*)d_in[0];
  const float* W = (const float*)d_in[1];
  const float* bias = (const float*)d_in[2];
  const float* B_lora = (const float*)d_in[3];
  const float* A_lora = (const float*)d_in[4];
  const float* dbias = (const float*)d_in[5];
  float* out = (float*)d_out;

  const size_t NEED = (size_t)M_DIM * K_DIM * 2 + (size_t)N_DIM * K_DIM * 2;  // 96 MiB
  if (ws_size >= NEED) {
    unsigned short* xb = (unsigned short*)d_ws;
    unsigned short* wb = xb + (size_t)M_DIM * K_DIM;
    cvt_x_kernel<<<2048, 256, 0, stream>>>(x, xb);
    build_wb_kernel<<<dim3(64, 64), 256, 0, stream>>>(W, B_lora, A_lora, wb);
    gemm_kernel<<<(M_DIM / 256) * (N_DIM / 256), 512, 0, stream>>>(xb, wb, bias, dbias, out);
  } else {
    float* xa = (float*)d_ws;
    xa_kernel<<<M_DIM, 256, 0, stream>>>(x, A_lora, xa);
    fgemm_kernel<<<(M_DIM / 64) * (N_DIM / 64), 256, 0, stream>>>(x, W, bias, B_lora, dbias, xa, out);
  }
}